// Round 6
// baseline (434.606 us; speedup 1.0000x reference)
//
#include <hip/hip_runtime.h>
#include <hip/hip_bf16.h>
#include <hip/hip_fp16.h>

typedef __hip_bfloat16 bf16;
typedef __attribute__((ext_vector_type(8))) short short8;   // 8 bf16 raw (4 VGPRs)
typedef __attribute__((ext_vector_type(4))) float f32x4;

__device__ __forceinline__ float braw2f(unsigned short u) {
    return __uint_as_float(((unsigned int)u) << 16);
}
__device__ __forceinline__ unsigned short f2braw(float f) {
    bf16 b = __float2bfloat16(f);
    return *(unsigned short*)&b;
}
__device__ __forceinline__ unsigned int pack2(float lo, float hi) {
    return (unsigned int)f2braw(lo) | ((unsigned int)f2braw(hi) << 16);
}
__device__ __forceinline__ float h2f(unsigned short u) {
    __half h = *(__half*)&u;
    return __half2float(h);
}

#define LN2F 0.69314718055994531f
// shifted softplus via native HW transcendentals (v_exp/v_log). Stable: arg<=0.
__device__ __forceinline__ float ssp(float x) {
    return fmaxf(x, 0.0f) + __logf(1.0f + __expf(-fabsf(x))) - LN2F;
}

// MFMA linear (round-8, verified): Y = (ACT? ssp:id)(X @ W^T + B), K=N=128.
// Block = 64 rows; in-place safe (block-private rows + barrier).
template<bool ACT, bool OUT_BF16>
__global__ __launch_bounds__(256) void linear128_mfma_kernel(
    const float* __restrict__ X, const float* __restrict__ W, const float* __restrict__ Bias,
    void* __restrict__ Yv, int n_rows)
{
    __shared__ unsigned short wls[128 * 128];
    __shared__ unsigned short xs[64 * 128];
    __shared__ float bls[128];

    const float4* W4 = (const float4*)W;
    for (int i = threadIdx.x; i < 128 * 32; i += 256) {
        float4 w = W4[i];
        ushort4 s; s.x = f2braw(w.x); s.y = f2braw(w.y); s.z = f2braw(w.z); s.w = f2braw(w.w);
        *(ushort4*)&wls[i * 4] = s;
    }
    if (threadIdx.x < 128) bls[threadIdx.x] = Bias[threadIdx.x];

    const int base = blockIdx.x * 64;
    const float4* X4 = (const float4*)X;
    for (int i = threadIdx.x; i < 64 * 32; i += 256) {
        int r = i >> 5, k4 = i & 31;
        int row = base + r;
        float4 v = (row < n_rows) ? X4[(size_t)row * 32 + k4] : make_float4(0.f, 0.f, 0.f, 0.f);
        ushort4 s; s.x = f2braw(v.x); s.y = f2braw(v.y); s.z = f2braw(v.z); s.w = f2braw(v.w);
        *(ushort4*)&xs[r * 128 + k4 * 4] = s;
    }
    __syncthreads();

    const int wv = threadIdx.x >> 6;
    const int l  = threadIdx.x & 63;
    const int lm = l & 15;
    const int lq = l >> 4;

    short8 a[4];
    #pragma unroll
    for (int kk = 0; kk < 4; ++kk)
        a[kk] = *(const short8*)&xs[(wv * 16 + lm) * 128 + kk * 32 + lq * 8];

    f32x4 acc[8];
    #pragma unroll
    for (int ct = 0; ct < 8; ++ct) {
        f32x4 c = {0.f, 0.f, 0.f, 0.f};
        #pragma unroll
        for (int kk = 0; kk < 4; ++kk) {
            short8 b = *(const short8*)&wls[(ct * 16 + lm) * 128 + kk * 32 + lq * 8];
            c = __builtin_amdgcn_mfma_f32_16x16x32_bf16(a[kk], b, c, 0, 0, 0);
        }
        acc[ct] = c;
    }

    #pragma unroll
    for (int ct = 0; ct < 8; ++ct) {
        int col = ct * 16 + lm;
        float bia = bls[col];
        #pragma unroll
        for (int r = 0; r < 4; ++r) {
            int row = base + wv * 16 + lq * 4 + r;
            if (row < n_rows) {
                float o = acc[ct][r] + bia;
                if (ACT) o = ssp(o);
                if (OUT_BF16) ((unsigned short*)Yv)[(size_t)row * 128 + col] = f2braw(o);
                else          ((float*)Yv)[(size_t)row * 128 + col] = o;
            }
        }
    }
}

// ---- counting sort by idx_i ----

__global__ __launch_bounds__(256) void zero_int_kernel(int* __restrict__ p, int n) {
    int i = blockIdx.x * 256 + threadIdx.x;
    if (i < n) p[i] = 0;
}

// zero two buffers in one launch (fewer kernel boundaries)
__global__ __launch_bounds__(256) void zero2_kernel(
    int* __restrict__ a, int na, int* __restrict__ b, int nb)
{
    int i = blockIdx.x * 256 + threadIdx.x;
    if (i < na) a[i] = 0;
    int j = i - na;
    if (j >= 0 && j < nb) b[j] = 0;
}

__global__ __launch_bounds__(256) void hist_kernel(
    const int* __restrict__ idx_i, int* __restrict__ cnt, int n_pairs, int n_atoms)
{
    for (int p = blockIdx.x * 256 + threadIdx.x; p < n_pairs; p += gridDim.x * 256) {
        int ai = idx_i[p];
        if ((unsigned)ai < (unsigned)n_atoms) atomicAdd(&cnt[ai], 1);
    }
}

__global__ __launch_bounds__(1024) void scan1_kernel(
    const int* __restrict__ cnt, int* __restrict__ offs, int* __restrict__ partials, int n)
{
    __shared__ int sm[1024];
    int t = threadIdx.x, idx = blockIdx.x * 1024 + t;
    int v = (idx < n) ? cnt[idx] : 0;
    sm[t] = v;
    __syncthreads();
    #pragma unroll
    for (int d = 1; d < 1024; d <<= 1) {
        int tmp = (t >= d) ? sm[t - d] : 0;
        __syncthreads();
        sm[t] += tmp;
        __syncthreads();
    }
    if (idx < n) offs[idx] = sm[t] - v;
    if (t == 1023) partials[blockIdx.x] = sm[1023];
}

__global__ __launch_bounds__(64) void scan2_kernel(
    int* __restrict__ partials, int* __restrict__ offs, int nb, int n)
{
    __shared__ int sm[64];
    int t = threadIdx.x;
    int v = (t < nb) ? partials[t] : 0;
    sm[t] = v;
    __syncthreads();
    #pragma unroll
    for (int d = 1; d < 64; d <<= 1) {
        int tmp = (t >= d) ? sm[t - d] : 0;
        __syncthreads();
        sm[t] += tmp;
        __syncthreads();
    }
    if (t < nb) partials[t] = sm[t] - v;
    if (t == 63) offs[n] = sm[63];
}

__global__ __launch_bounds__(1024) void scan3_kernel(
    int* __restrict__ offs, int* __restrict__ cur, const int* __restrict__ partials, int n)
{
    int idx = blockIdx.x * 1024 + threadIdx.x;
    if (idx < n) {
        int o = offs[idx] + partials[blockIdx.x];
        offs[idx] = o;
        cur[idx] = o;
    }
}

// ---------- PAYLOAD PATH: physically sort pair payload ----------
// payload[pos] = { f_ij bf16 x20 (40 B) | idx_j int (4 B) | rcut f32 (4 B) } = 48 B
// WRITE_ATOM: also fill pair_atom[pos] = owning atom (tier-1 fused path only).
// Block 0 additionally zeroes a 17-record (816 B) slack region after the payload so
// that MFMA A-fragment / rcut over-reads stay in-bounds.
template<bool WRITE_ATOM>
__global__ __launch_bounds__(256) void scatter_pay_kernel(
    const float* __restrict__ f_ij, const int* __restrict__ idx_i, const int* __restrict__ idx_j,
    const float* __restrict__ rcut, int* __restrict__ cur, uint4* __restrict__ pay,
    int* __restrict__ pair_atom, int n_pairs, int n_atoms)
{
    if (blockIdx.x == 0 && threadIdx.x < 204) {
        ((int*)(pay + (size_t)n_pairs * 3))[threadIdx.x] = 0;
    }
    for (int p = blockIdx.x * 256 + threadIdx.x; p < n_pairs; p += gridDim.x * 256) {
        int ai = idx_i[p];
        if ((unsigned)ai >= (unsigned)n_atoms) continue;
        int pos = atomicAdd(&cur[ai], 1);
        const float4* fr = (const float4*)(f_ij + (size_t)p * 20);
        float4 f0 = fr[0], f1 = fr[1], f2 = fr[2], f3 = fr[3], f4 = fr[4];
        uint4 q0, q1, q2;
        q0.x = pack2(f0.x, f0.y); q0.y = pack2(f0.z, f0.w);
        q0.z = pack2(f1.x, f1.y); q0.w = pack2(f1.z, f1.w);
        q1.x = pack2(f2.x, f2.y); q1.y = pack2(f2.z, f2.w);
        q1.z = pack2(f3.x, f3.y); q1.w = pack2(f3.z, f3.w);
        q2.x = pack2(f4.x, f4.y); q2.y = pack2(f4.z, f4.w);
        q2.z = (unsigned int)idx_j[p];
        q2.w = __float_as_uint(rcut[p]);
        uint4* dst = pay + (size_t)pos * 3;
        dst[0] = q0; dst[1] = q1; dst[2] = q2;
        if (WRITE_ATOM) pair_atom[pos] = ai;
    }
}

// ---------- FUSED v3: prefetched, barrier-free, W_f in registers ----------
// Block = 4 independent waves; wave owns 16*NITER consecutive sorted pairs.
// Per-wave setup (once): B-fragments of W_f (col=ct*16+lm, k=lq*8..+8, k>=20 zero)
//   and bias in registers — no W_f LDS, no block barrier at all.
// Per 16-pair chunk:
//   1. meta: pair_atom -> SGPR (readfirstlane), idx_j -> h-gather ISSUED IMMEDIATELY
//      into hreg[16] VGPRs (T14 issue-early).
//   2. phase A (covers gather latency): A-frag from payload (k>=20 zeroed in regs —
//      rcut low bits can encode bf16 NaN; 0*NaN=NaN, round-1 bug), 8x
//      mfma_f32_16x16x32_bf16, ssp*rcut epilogue -> fp16 wij in wave-private LDS.
//   3. lgkmcnt(0) fence (rule #18: stop compiler hoisting ds_reads above writes).
//   4. phase B: hreg[k] (already landed) x wij LDS dword, 2 FMAs/pair; accumulators
//      carried across chunks, atomicAdd flush only on atom change (agg pre-zeroed).
#define FP_NITER 4

__global__ __launch_bounds__(256, 4) void fused_pair_kernel(
    const uint4* __restrict__ pay, const int* __restrict__ pair_atom,
    const float* __restrict__ W_f, const float* __restrict__ b_f,
    const unsigned int* __restrict__ hb32, float* __restrict__ agg, int n_pairs)
{
    __shared__ unsigned short wij[4][16 * 132];  // per-WAVE fp16 Wij [pair][ch], pad 132

    const int wv = threadIdx.x >> 6;
    const int l  = threadIdx.x & 63;
    const int lm = l & 15;
    const int lq = l >> 4;

    // ---- once per wave: W_f B-fragments + bias in registers ----
    short8 bfrag[8];
    float bias[8];
    #pragma unroll
    for (int ct = 0; ct < 8; ++ct) {
        const int col = ct * 16 + lm;
        short8 b;
        #pragma unroll
        for (int e = 0; e < 8; ++e) {
            int k = lq * 8 + e;
            float v = (k < 20) ? W_f[col * 20 + k] : 0.f;
            b[e] = (short)f2braw(v);
        }
        bfrag[ct] = b;
        bias[ct] = b_f[col];
    }

    const unsigned int* payu = (const unsigned int*)pay;
    const int base = (blockIdx.x * 4 + wv) * (16 * FP_NITER);
    float a0 = 0.f, a1 = 0.f;
    int cura = -1;

    for (int t = 0; t < FP_NITER; ++t) {
        const int p0 = base + t * 16;
        if (p0 >= n_pairs) break;
        int nv = n_pairs - p0;
        if (nv > 16) nv = 16;

        // ---- 1. meta + issue h-gathers early ----
        int pa[16];
        unsigned int hreg[16];
        #pragma unroll
        for (int k = 0; k < 16; ++k) {
            int p = p0 + k;
            bool valid = p < n_pairs;
            pa[k] = __builtin_amdgcn_readfirstlane(valid ? pair_atom[p] : -1);
            int ajk = valid ? (int)payu[(size_t)p * 12 + 10] : 0;
            hreg[k] = hb32[(size_t)ajk * 64 + l];
        }

        // ---- 2. phase A: Wij tile (covers the gather latency) ----
        const char* rec = (const char*)pay + (size_t)(p0 + lm) * 48;
        short8 a = *(const short8*)(rec + lq * 16);
        if (lq == 2) { a[4] = 0; a[5] = 0; a[6] = 0; a[7] = 0; }
        if (lq == 3) { a[0]=0; a[1]=0; a[2]=0; a[3]=0; a[4]=0; a[5]=0; a[6]=0; a[7]=0; }

        float rc[4];
        #pragma unroll
        for (int r = 0; r < 4; ++r) {
            int p = p0 + lq * 4 + r;
            rc[r] = (p < n_pairs) ? ((const float*)pay)[(size_t)p * 12 + 11] : 0.f;
        }

        #pragma unroll
        for (int ct = 0; ct < 8; ++ct) {
            f32x4 z = {0.f, 0.f, 0.f, 0.f};
            f32x4 acc = __builtin_amdgcn_mfma_f32_16x16x32_bf16(a, bfrag[ct], z, 0, 0, 0);
            #pragma unroll
            for (int r = 0; r < 4; ++r) {
                float o = ssp(acc[r] + bias[ct]) * rc[r];
                __half hh = __float2half(o);
                wij[wv][(lq * 4 + r) * 132 + ct * 16 + lm] = *(unsigned short*)&hh;
            }
        }

        // ---- 3. fence ----
        asm volatile("s_waitcnt lgkmcnt(0)" ::: "memory");

        // ---- 4. phase B: consume prefetched hreg + wij LDS ----
        #pragma unroll 4
        for (int k = 0; k < nv; ++k) {
            int p_a = pa[k];
            if (p_a != cura) {
                if (cura >= 0) {
                    atomicAdd(&agg[(size_t)cura * 128 + 2 * l], a0);
                    atomicAdd(&agg[(size_t)cura * 128 + 2 * l + 1], a1);
                }
                a0 = 0.f; a1 = 0.f; cura = p_a;
            }
            unsigned int h = hreg[k];
            unsigned int w = *(const unsigned int*)&wij[wv][k * 132 + 2 * l];
            a0 += __uint_as_float(h << 16) * h2f((unsigned short)(w & 0xffffu));
            a1 += __uint_as_float(h & 0xffff0000u) * h2f((unsigned short)(w >> 16));
        }
    }
    if (cura >= 0) {
        atomicAdd(&agg[(size_t)cura * 128 + 2 * l], a0);
        atomicAdd(&agg[(size_t)cura * 128 + 2 * l + 1], a1);
    }
}

// ---------- TIER-2 (proven 367 µs): fused segment over sorted payload ----------
__global__ __launch_bounds__(256) void segment_pay_kernel(
    const uint4* __restrict__ pay, const float* __restrict__ W_f,
    const float* __restrict__ b_f, const unsigned int* __restrict__ hb32,
    const int* __restrict__ offs, float* __restrict__ agg, int n_atoms)
{
    const int wave = (blockIdx.x * 256 + threadIdx.x) >> 6;
    const int lane = threadIdx.x & 63;
    if (wave >= n_atoms) return;

    const int c0 = 2 * lane;
    float w0[20], w1[20];
    #pragma unroll
    for (int r = 0; r < 20; ++r) {
        w0[r] = W_f[c0 * 20 + r];
        w1[r] = W_f[(c0 + 1) * 20 + r];
    }
    const float b0 = b_f[c0], b1 = b_f[c0 + 1];

    const int cs = offs[wave], ce = offs[wave + 1];
    float acc0 = 0.f, acc1 = 0.f;

    int s = cs;
    for (; s + 2 <= ce; s += 2) {
        const uint4* pA = pay + (size_t)s * 3;
        const uint4* pB = pA + 3;
        uint4 qA0 = pA[0], qA1 = pA[1], qA2 = pA[2];
        uint4 qB0 = pB[0], qB1 = pB[1], qB2 = pB[2];
        unsigned int uA[10] = {qA0.x,qA0.y,qA0.z,qA0.w,qA1.x,qA1.y,qA1.z,qA1.w,qA2.x,qA2.y};
        unsigned int uB[10] = {qB0.x,qB0.y,qB0.z,qB0.w,qB1.x,qB1.y,qB1.z,qB1.w,qB2.x,qB2.y};
        float a0A = b0, a1A = b1, a0B = b0, a1B = b1;
        #pragma unroll
        for (int r = 0; r < 10; ++r) {
            float loA = __uint_as_float(uA[r] << 16);
            float hiA = __uint_as_float(uA[r] & 0xffff0000u);
            float loB = __uint_as_float(uB[r] << 16);
            float hiB = __uint_as_float(uB[r] & 0xffff0000u);
            a0A += loA * w0[2*r];     a1A += loA * w1[2*r];
            a0A += hiA * w0[2*r + 1]; a1A += hiA * w1[2*r + 1];
            a0B += loB * w0[2*r];     a1B += loB * w1[2*r];
            a0B += hiB * w0[2*r + 1]; a1B += hiB * w1[2*r + 1];
        }
        float rcA = __uint_as_float(qA2.w), rcB = __uint_as_float(qB2.w);
        float wv0A = ssp(a0A) * rcA, wv1A = ssp(a1A) * rcA;
        float wv0B = ssp(a0B) * rcB, wv1B = ssp(a1B) * rcB;
        unsigned int hA = hb32[(size_t)(int)qA2.z * 64 + lane];
        unsigned int hB = hb32[(size_t)(int)qB2.z * 64 + lane];
        acc0 += __uint_as_float(hA << 16) * wv0A + __uint_as_float(hB << 16) * wv0B;
        acc1 += __uint_as_float(hA & 0xffff0000u) * wv1A + __uint_as_float(hB & 0xffff0000u) * wv1B;
    }
    if (s < ce) {
        const uint4* pA = pay + (size_t)s * 3;
        uint4 q0 = pA[0], q1 = pA[1], q2 = pA[2];
        unsigned int u[10] = {q0.x,q0.y,q0.z,q0.w,q1.x,q1.y,q1.z,q1.w,q2.x,q2.y};
        float a0 = b0, a1 = b1;
        #pragma unroll
        for (int r = 0; r < 10; ++r) {
            float lo = __uint_as_float(u[r] << 16);
            float hi = __uint_as_float(u[r] & 0xffff0000u);
            a0 += lo * w0[2*r];     a1 += lo * w1[2*r];
            a0 += hi * w0[2*r + 1]; a1 += hi * w1[2*r + 1];
        }
        float rc = __uint_as_float(q2.w);
        float wv0 = ssp(a0) * rc, wv1 = ssp(a1) * rc;
        unsigned int h = hb32[(size_t)(int)q2.z * 64 + lane];
        acc0 += __uint_as_float(h << 16) * wv0;
        acc1 += __uint_as_float(h & 0xffff0000u) * wv1;
    }

    *(float2*)&agg[(size_t)wave * 128 + c0] = make_float2(acc0, acc1);
}

// ---------- TIER-3 FALLBACK (proven): perm-indirected segment ----------
__global__ __launch_bounds__(256) void scatter_kernel(
    const int* __restrict__ idx_i, int* __restrict__ cur, int* __restrict__ perm,
    int n_pairs, int n_atoms)
{
    for (int p = blockIdx.x * 256 + threadIdx.x; p < n_pairs; p += gridDim.x * 256) {
        int ai = idx_i[p];
        if ((unsigned)ai < (unsigned)n_atoms) {
            int pos = atomicAdd(&cur[ai], 1);
            perm[pos] = p;
        }
    }
}

__global__ __launch_bounds__(256) void segment_kernel(
    const float* __restrict__ f_ij, const int* __restrict__ idx_j,
    const float* __restrict__ rcut, const float* __restrict__ W_f,
    const float* __restrict__ b_f, const unsigned short* __restrict__ hb,
    const int* __restrict__ offs, const int* __restrict__ perm,
    float* __restrict__ agg, int n_atoms)
{
    const int wave = (blockIdx.x * 256 + threadIdx.x) >> 6;
    const int lane = threadIdx.x & 63;
    if (wave >= n_atoms) return;

    float w0[20], w1[20];
    #pragma unroll
    for (int r = 0; r < 20; ++r) {
        w0[r] = W_f[lane * 20 + r];
        w1[r] = W_f[(lane + 64) * 20 + r];
    }
    const float b0 = b_f[lane], b1 = b_f[lane + 64];

    const int cs = offs[wave], ce = offs[wave + 1];
    float acc0 = 0.f, acc1 = 0.f;

    int s = cs;
    for (; s + 2 <= ce; s += 2) {
        int pA = perm[s], pB = perm[s + 1];
        int ajA = idx_j[pA], ajB = idx_j[pB];
        float rcA = rcut[pA], rcB = rcut[pB];
        const float4* frA = (const float4*)(f_ij + (size_t)pA * 20);
        const float4* frB = (const float4*)(f_ij + (size_t)pB * 20);
        float a0A = b0, a1A = b1, a0B = b0, a1B = b1;
        #pragma unroll
        for (int q = 0; q < 5; ++q) {
            float4 fA = frA[q], fB = frB[q];
            a0A += fA.x * w0[4*q+0]; a1A += fA.x * w1[4*q+0];
            a0A += fA.y * w0[4*q+1]; a1A += fA.y * w1[4*q+1];
            a0A += fA.z * w0[4*q+2]; a1A += fA.z * w1[4*q+2];
            a0A += fA.w * w0[4*q+3]; a1A += fA.w * w1[4*q+3];
            a0B += fB.x * w0[4*q+0]; a1B += fB.x * w1[4*q+0];
            a0B += fB.y * w0[4*q+1]; a1B += fB.y * w1[4*q+1];
            a0B += fB.z * w0[4*q+2]; a1B += fB.z * w1[4*q+2];
            a0B += fB.w * w0[4*q+3]; a1B += fB.w * w1[4*q+3];
        }
        float wv0A = ssp(a0A) * rcA, wv1A = ssp(a1A) * rcA;
        float wv0B = ssp(a0B) * rcB, wv1B = ssp(a1B) * rcB;
        float h0A = braw2f(hb[(size_t)ajA * 128 + lane]);
        float h1A = braw2f(hb[(size_t)ajA * 128 + 64 + lane]);
        float h0B = braw2f(hb[(size_t)ajB * 128 + lane]);
        float h1B = braw2f(hb[(size_t)ajB * 128 + 64 + lane]);
        acc0 += h0A * wv0A + h0B * wv0B;
        acc1 += h1A * wv1A + h1B * wv1B;
    }
    if (s < ce) {
        int p = perm[s];
        int aj = idx_j[p];
        float rc = rcut[p];
        const float4* fr = (const float4*)(f_ij + (size_t)p * 20);
        float a0 = b0, a1 = b1;
        #pragma unroll
        for (int q = 0; q < 5; ++q) {
            float4 fv = fr[q];
            a0 += fv.x * w0[4*q+0]; a1 += fv.x * w1[4*q+0];
            a0 += fv.y * w0[4*q+1]; a1 += fv.y * w1[4*q+1];
            a0 += fv.z * w0[4*q+2]; a1 += fv.z * w1[4*q+2];
            a0 += fv.w * w0[4*q+3]; a1 += fv.w * w1[4*q+3];
        }
        float wv0 = ssp(a0) * rc, wv1 = ssp(a1) * rc;
        acc0 += braw2f(hb[(size_t)aj * 128 + lane]) * wv0;
        acc1 += braw2f(hb[(size_t)aj * 128 + 64 + lane]) * wv1;
    }

    agg[(size_t)wave * 128 + lane]      = acc0;
    agg[(size_t)wave * 128 + 64 + lane] = acc1;
}

static inline size_t align_up(size_t v, size_t a) { return (v + a - 1) & ~(a - 1); }

extern "C" void kernel_launch(void* const* d_in, const int* in_sizes, int n_in,
                              void* d_out, int out_size, void* d_ws, size_t ws_size,
                              hipStream_t stream) {
    const float* x     = (const float*)d_in[0];
    const float* f_ij  = (const float*)d_in[1];
    const int*   idx_i = (const int*)d_in[2];
    const int*   idx_j = (const int*)d_in[3];
    const float* rcut  = (const float*)d_in[4];
    const float* W_in  = (const float*)d_in[5];
    const float* b_in  = (const float*)d_in[6];
    const float* W_f   = (const float*)d_in[7];
    const float* b_f   = (const float*)d_in[8];
    const float* W_out = (const float*)d_in[9];
    const float* b_out = (const float*)d_in[10];

    const int n_atoms = in_sizes[0] / 128;   // 40000
    const int n_pairs = in_sizes[2];         // 640000
    const int nscan = (n_atoms + 1023) / 1024;
    const int mfma_grid = (n_atoms + 63) / 64;

    // Shared ws layout (tiers 1 & 2)
    size_t off_hb   = 0;
    size_t off_offs = align_up(off_hb + (size_t)n_atoms * 128 * 2, 16);
    size_t off_cur  = align_up(off_offs + (size_t)(n_atoms + 1) * 4, 16);
    size_t off_part = align_up(off_cur + (size_t)n_atoms * 4, 16);
    size_t off_pay  = align_up(off_part + (size_t)nscan * 4, 64);
    size_t need_pay = off_pay + (size_t)n_pairs * 48;                 // tier-2 need
    size_t off_pa   = align_up(off_pay + (size_t)n_pairs * 48 + 816, 256);
    size_t need_fused = off_pa + (size_t)(n_pairs + 64) * 4;          // tier-1 need (~44 MB)

    if (ws_size >= need_fused) {
        // ---------- tier-1: fused MFMA filter-GEMM + segment (prefetched v3) ----------
        unsigned short* hb  = (unsigned short*)((char*)d_ws + off_hb);
        int*   offs = (int*)((char*)d_ws + off_offs);
        int*   cur  = (int*)((char*)d_ws + off_cur);
        int*   part = (int*)((char*)d_ws + off_part);
        uint4* pay  = (uint4*)((char*)d_ws + off_pay);
        int*   pair_atom = (int*)((char*)d_ws + off_pa);
        float* agg = (float*)d_out;

        linear128_mfma_kernel<false, true><<<dim3(mfma_grid), dim3(256), 0, stream>>>(
            x, W_in, b_in, (void*)hb, n_atoms);

        // zero agg (atomically accumulated) + cur in one launch
        zero2_kernel<<<dim3((n_atoms * 128 + n_atoms + 255) / 256), dim3(256), 0, stream>>>(
            (int*)agg, n_atoms * 128, cur, n_atoms);

        hist_kernel<<<dim3(1024), dim3(256), 0, stream>>>(idx_i, cur, n_pairs, n_atoms);
        scan1_kernel<<<dim3(nscan), dim3(1024), 0, stream>>>(cur, offs, part, n_atoms);
        scan2_kernel<<<dim3(1), dim3(64), 0, stream>>>(part, offs, nscan, n_atoms);
        scan3_kernel<<<dim3(nscan), dim3(1024), 0, stream>>>(offs, cur, part, n_atoms);
        scatter_pay_kernel<true><<<dim3(1024), dim3(256), 0, stream>>>(
            f_ij, idx_i, idx_j, rcut, cur, pay, pair_atom, n_pairs, n_atoms);

        int fp_blocks = (n_pairs + 64 * FP_NITER - 1) / (64 * FP_NITER);
        fused_pair_kernel<<<dim3(fp_blocks), dim3(256), 0, stream>>>(
            pay, pair_atom, W_f, b_f, (const unsigned int*)hb, agg, n_pairs);

        linear128_mfma_kernel<true, false><<<dim3(mfma_grid), dim3(256), 0, stream>>>(
            agg, W_out, b_out, d_out, n_atoms);
    } else if (ws_size >= need_pay) {
        // ---------- tier-2: proven 367 µs payload path ----------
        unsigned short* hb = (unsigned short*)((char*)d_ws + off_hb);
        int*  offs = (int*)((char*)d_ws + off_offs);
        int*  cur  = (int*)((char*)d_ws + off_cur);
        int*  part = (int*)((char*)d_ws + off_part);
        uint4* pay = (uint4*)((char*)d_ws + off_pay);
        float* agg = (float*)d_out;

        linear128_mfma_kernel<false, true><<<dim3(mfma_grid), dim3(256), 0, stream>>>(
            x, W_in, b_in, (void*)hb, n_atoms);

        zero_int_kernel<<<dim3((n_atoms + 255) / 256), dim3(256), 0, stream>>>(cur, n_atoms);
        hist_kernel<<<dim3(1024), dim3(256), 0, stream>>>(idx_i, cur, n_pairs, n_atoms);
        scan1_kernel<<<dim3(nscan), dim3(1024), 0, stream>>>(cur, offs, part, n_atoms);
        scan2_kernel<<<dim3(1), dim3(64), 0, stream>>>(part, offs, nscan, n_atoms);
        scan3_kernel<<<dim3(nscan), dim3(1024), 0, stream>>>(offs, cur, part, n_atoms);
        scatter_pay_kernel<false><<<dim3(1024), dim3(256), 0, stream>>>(
            f_ij, idx_i, idx_j, rcut, cur, pay, (int*)nullptr, n_pairs, n_atoms);

        segment_pay_kernel<<<dim3((n_atoms + 3) / 4), dim3(256), 0, stream>>>(
            pay, W_f, b_f, (const unsigned int*)hb, offs, agg, n_atoms);

        linear128_mfma_kernel<true, false><<<dim3(mfma_grid), dim3(256), 0, stream>>>(
            agg, W_out, b_out, d_out, n_atoms);
    } else {
        // ---------- tier-3: exact round-8 pipeline (proven 419 µs) ----------
        size_t o_h    = 0;
        size_t o_offs = o_h + (size_t)n_atoms * 128 * 2;
        size_t o_cur  = o_offs + (size_t)(n_atoms + 1) * 4;
        size_t o_perm = o_cur + (size_t)n_atoms * 4;
        size_t o_part = o_perm + (size_t)n_pairs * 4;
        unsigned short* hb = (unsigned short*)((char*)d_ws + o_h);
        int* offs = (int*)((char*)d_ws + o_offs);
        int* cur  = (int*)((char*)d_ws + o_cur);
        int* perm = (int*)((char*)d_ws + o_perm);
        int* part = (int*)((char*)d_ws + o_part);
        float* agg = (float*)d_out;

        linear128_mfma_kernel<false, true><<<dim3(mfma_grid), dim3(256), 0, stream>>>(
            x, W_in, b_in, (void*)hb, n_atoms);

        zero_int_kernel<<<dim3((n_atoms + 255) / 256), dim3(256), 0, stream>>>(cur, n_atoms);
        hist_kernel<<<dim3(1024), dim3(256), 0, stream>>>(idx_i, cur, n_pairs, n_atoms);
        scan1_kernel<<<dim3(nscan), dim3(1024), 0, stream>>>(cur, offs, part, n_atoms);
        scan2_kernel<<<dim3(1), dim3(64), 0, stream>>>(part, offs, nscan, n_atoms);
        scan3_kernel<<<dim3(nscan), dim3(1024), 0, stream>>>(offs, cur, part, n_atoms);
        scatter_kernel<<<dim3(1024), dim3(256), 0, stream>>>(idx_i, cur, perm, n_pairs, n_atoms);

        segment_kernel<<<dim3((n_atoms + 3) / 4), dim3(256), 0, stream>>>(
            f_ij, idx_j, rcut, W_f, b_f, hb, offs, perm, agg, n_atoms);

        linear128_mfma_kernel<true, false><<<dim3(mfma_grid), dim3(256), 0, stream>>>(
            agg, W_out, b_out, d_out, n_atoms);
    }
}

// Round 7
// 326.772 us; speedup vs baseline: 1.3300x; 1.3300x over previous
//
#include <hip/hip_runtime.h>
#include <hip/hip_bf16.h>
#include <hip/hip_fp16.h>

typedef __hip_bfloat16 bf16;
typedef __attribute__((ext_vector_type(8))) short short8;   // 8 bf16 raw (4 VGPRs)
typedef __attribute__((ext_vector_type(4))) float f32x4;
typedef __attribute__((ext_vector_type(2))) _Float16 h16x2; // packed f16 pair

#if defined(__has_builtin)
#if __has_builtin(__builtin_amdgcn_fdot2)
#define HAVE_FDOT2 1
#endif
#endif

__device__ __forceinline__ float braw2f(unsigned short u) {
    return __uint_as_float(((unsigned int)u) << 16);
}
__device__ __forceinline__ unsigned short f2braw(float f) {
    bf16 b = __float2bfloat16(f);
    return *(unsigned short*)&b;
}
__device__ __forceinline__ unsigned int pack2(float lo, float hi) {
    return (unsigned int)f2braw(lo) | ((unsigned int)f2braw(hi) << 16);
}
// pack two floats as f16 pair (payload format for the fdot2 segment kernel)
__device__ __forceinline__ unsigned int pack2h(float lo, float hi) {
    __half l = __float2half(lo), h = __float2half(hi);
    return (unsigned int)*(unsigned short*)&l | ((unsigned int)*(unsigned short*)&h << 16);
}
// v_dot2_f32_f16: c += a.x*b.x + a.y*b.y in ONE VALU op (f32 accumulate)
__device__ __forceinline__ float fdot2(h16x2 a, h16x2 b, float c) {
#ifdef HAVE_FDOT2
    return __builtin_amdgcn_fdot2(a, b, c, false);
#else
    return c + (float)a[0] * (float)b[0] + (float)a[1] * (float)b[1];
#endif
}
__device__ __forceinline__ h16x2 u2h2(unsigned int u) {
    union { unsigned int u; h16x2 h; } cv; cv.u = u; return cv.h;
}

#define LN2F 0.69314718055994531f
// shifted softplus via native HW transcendentals (v_exp/v_log). Stable: arg<=0.
__device__ __forceinline__ float ssp(float x) {
    return fmaxf(x, 0.0f) + __logf(1.0f + __expf(-fabsf(x))) - LN2F;
}

// MFMA linear (round-8, verified): Y = (ACT? ssp:id)(X @ W^T + B), K=N=128.
// Block = 64 rows; in-place safe (block-private rows + barrier).
template<bool ACT, bool OUT_BF16>
__global__ __launch_bounds__(256) void linear128_mfma_kernel(
    const float* __restrict__ X, const float* __restrict__ W, const float* __restrict__ Bias,
    void* __restrict__ Yv, int n_rows)
{
    __shared__ unsigned short wls[128 * 128];
    __shared__ unsigned short xs[64 * 128];
    __shared__ float bls[128];

    const float4* W4 = (const float4*)W;
    for (int i = threadIdx.x; i < 128 * 32; i += 256) {
        float4 w = W4[i];
        ushort4 s; s.x = f2braw(w.x); s.y = f2braw(w.y); s.z = f2braw(w.z); s.w = f2braw(w.w);
        *(ushort4*)&wls[i * 4] = s;
    }
    if (threadIdx.x < 128) bls[threadIdx.x] = Bias[threadIdx.x];

    const int base = blockIdx.x * 64;
    const float4* X4 = (const float4*)X;
    for (int i = threadIdx.x; i < 64 * 32; i += 256) {
        int r = i >> 5, k4 = i & 31;
        int row = base + r;
        float4 v = (row < n_rows) ? X4[(size_t)row * 32 + k4] : make_float4(0.f, 0.f, 0.f, 0.f);
        ushort4 s; s.x = f2braw(v.x); s.y = f2braw(v.y); s.z = f2braw(v.z); s.w = f2braw(v.w);
        *(ushort4*)&xs[r * 128 + k4 * 4] = s;
    }
    __syncthreads();

    const int wv = threadIdx.x >> 6;
    const int l  = threadIdx.x & 63;
    const int lm = l & 15;
    const int lq = l >> 4;

    short8 a[4];
    #pragma unroll
    for (int kk = 0; kk < 4; ++kk)
        a[kk] = *(const short8*)&xs[(wv * 16 + lm) * 128 + kk * 32 + lq * 8];

    f32x4 acc[8];
    #pragma unroll
    for (int ct = 0; ct < 8; ++ct) {
        f32x4 c = {0.f, 0.f, 0.f, 0.f};
        #pragma unroll
        for (int kk = 0; kk < 4; ++kk) {
            short8 b = *(const short8*)&wls[(ct * 16 + lm) * 128 + kk * 32 + lq * 8];
            c = __builtin_amdgcn_mfma_f32_16x16x32_bf16(a[kk], b, c, 0, 0, 0);
        }
        acc[ct] = c;
    }

    #pragma unroll
    for (int ct = 0; ct < 8; ++ct) {
        int col = ct * 16 + lm;
        float bia = bls[col];
        #pragma unroll
        for (int r = 0; r < 4; ++r) {
            int row = base + wv * 16 + lq * 4 + r;
            if (row < n_rows) {
                float o = acc[ct][r] + bia;
                if (ACT) o = ssp(o);
                if (OUT_BF16) ((unsigned short*)Yv)[(size_t)row * 128 + col] = f2braw(o);
                else          ((float*)Yv)[(size_t)row * 128 + col] = o;
            }
        }
    }
}

// ---- counting sort by idx_i ----

__global__ __launch_bounds__(256) void zero_int_kernel(int* __restrict__ p, int n) {
    int i = blockIdx.x * 256 + threadIdx.x;
    if (i < n) p[i] = 0;
}

__global__ __launch_bounds__(256) void hist_kernel(
    const int* __restrict__ idx_i, int* __restrict__ cnt, int n_pairs, int n_atoms)
{
    for (int p = blockIdx.x * 256 + threadIdx.x; p < n_pairs; p += gridDim.x * 256) {
        int ai = idx_i[p];
        if ((unsigned)ai < (unsigned)n_atoms) atomicAdd(&cnt[ai], 1);
    }
}

__global__ __launch_bounds__(1024) void scan1_kernel(
    const int* __restrict__ cnt, int* __restrict__ offs, int* __restrict__ partials, int n)
{
    __shared__ int sm[1024];
    int t = threadIdx.x, idx = blockIdx.x * 1024 + t;
    int v = (idx < n) ? cnt[idx] : 0;
    sm[t] = v;
    __syncthreads();
    #pragma unroll
    for (int d = 1; d < 1024; d <<= 1) {
        int tmp = (t >= d) ? sm[t - d] : 0;
        __syncthreads();
        sm[t] += tmp;
        __syncthreads();
    }
    if (idx < n) offs[idx] = sm[t] - v;
    if (t == 1023) partials[blockIdx.x] = sm[1023];
}

__global__ __launch_bounds__(64) void scan2_kernel(
    int* __restrict__ partials, int* __restrict__ offs, int nb, int n)
{
    __shared__ int sm[64];
    int t = threadIdx.x;
    int v = (t < nb) ? partials[t] : 0;
    sm[t] = v;
    __syncthreads();
    #pragma unroll
    for (int d = 1; d < 64; d <<= 1) {
        int tmp = (t >= d) ? sm[t - d] : 0;
        __syncthreads();
        sm[t] += tmp;
        __syncthreads();
    }
    if (t < nb) partials[t] = sm[t] - v;
    if (t == 63) offs[n] = sm[63];
}

__global__ __launch_bounds__(1024) void scan3_kernel(
    int* __restrict__ offs, int* __restrict__ cur, const int* __restrict__ partials, int n)
{
    int idx = blockIdx.x * 1024 + threadIdx.x;
    if (idx < n) {
        int o = offs[idx] + partials[blockIdx.x];
        offs[idx] = o;
        cur[idx] = o;
    }
}

// ---------- PAYLOAD PATH: physically sort pair payload ----------
// payload[pos] = { f_ij F16 x20 (40 B) | idx_j int (4 B) | rcut f32 (4 B) } = 48 B
// (f16, not bf16: feeds v_dot2_f32_f16 in the segment kernel with no unpacking;
// f16 also has 2 more mantissa bits than bf16 for f_ij in [0,1).)
// Block 0 additionally zeroes an 816 B slack region after the payload.
__global__ __launch_bounds__(256) void scatter_pay_kernel(
    const float* __restrict__ f_ij, const int* __restrict__ idx_i, const int* __restrict__ idx_j,
    const float* __restrict__ rcut, int* __restrict__ cur, uint4* __restrict__ pay,
    int n_pairs, int n_atoms)
{
    if (blockIdx.x == 0 && threadIdx.x < 204) {
        ((int*)(pay + (size_t)n_pairs * 3))[threadIdx.x] = 0;
    }
    for (int p = blockIdx.x * 256 + threadIdx.x; p < n_pairs; p += gridDim.x * 256) {
        int ai = idx_i[p];
        if ((unsigned)ai >= (unsigned)n_atoms) continue;
        int pos = atomicAdd(&cur[ai], 1);
        const float4* fr = (const float4*)(f_ij + (size_t)p * 20);
        float4 f0 = fr[0], f1 = fr[1], f2 = fr[2], f3 = fr[3], f4 = fr[4];
        uint4 q0, q1, q2;
        q0.x = pack2h(f0.x, f0.y); q0.y = pack2h(f0.z, f0.w);
        q0.z = pack2h(f1.x, f1.y); q0.w = pack2h(f1.z, f1.w);
        q1.x = pack2h(f2.x, f2.y); q1.y = pack2h(f2.z, f2.w);
        q1.z = pack2h(f3.x, f3.y); q1.w = pack2h(f3.z, f3.w);
        q2.x = pack2h(f4.x, f4.y); q2.y = pack2h(f4.z, f4.w);
        q2.z = (unsigned int)idx_j[p];
        q2.w = __float_as_uint(rcut[p]);
        uint4* dst = pay + (size_t)pos * 3;
        dst[0] = q0; dst[1] = q1; dst[2] = q2;
    }
}

// ---------- TIER-1: segment over sorted f16 payload, v_dot2_f32_f16 ----------
// Same proven structure as the 148 µs segment_pay (wave per atom, lane owns
// channels 2l,2l+1, 2-pair unroll, sequential uint4 payload loads, one coalesced
// 256 B h-gather per pair) — but the 20-rbf filter dot product is 20 fdot2 ops
// instead of 40 FMA + 40 shift/and unpacks. Per-pair VALU ~100 -> ~38 ops.
__global__ __launch_bounds__(256) void segment_pay_f16_kernel(
    const uint4* __restrict__ pay, const float* __restrict__ W_f,
    const float* __restrict__ b_f, const unsigned int* __restrict__ hb32,
    const int* __restrict__ offs, float* __restrict__ agg, int n_atoms)
{
    const int wave = (blockIdx.x * 256 + threadIdx.x) >> 6;
    const int lane = threadIdx.x & 63;
    if (wave >= n_atoms) return;

    const int c0 = 2 * lane;
    // packed W_f: w0p[r] = (W_f[c0][2r], W_f[c0][2r+1]) as f16 pair; w1p for c0+1
    h16x2 w0p[10], w1p[10];
    #pragma unroll
    for (int r = 0; r < 10; ++r) {
        h16x2 a, b;
        a[0] = (_Float16)W_f[c0 * 20 + 2 * r];
        a[1] = (_Float16)W_f[c0 * 20 + 2 * r + 1];
        b[0] = (_Float16)W_f[(c0 + 1) * 20 + 2 * r];
        b[1] = (_Float16)W_f[(c0 + 1) * 20 + 2 * r + 1];
        w0p[r] = a; w1p[r] = b;
    }
    const float b0 = b_f[c0], b1 = b_f[c0 + 1];

    const int cs = offs[wave], ce = offs[wave + 1];
    float acc0 = 0.f, acc1 = 0.f;

    int s = cs;
    for (; s + 2 <= ce; s += 2) {
        const uint4* pA = pay + (size_t)s * 3;
        const uint4* pB = pA + 3;
        uint4 qA0 = pA[0], qA1 = pA[1], qA2 = pA[2];
        uint4 qB0 = pB[0], qB1 = pB[1], qB2 = pB[2];
        unsigned int uA[10] = {qA0.x,qA0.y,qA0.z,qA0.w,qA1.x,qA1.y,qA1.z,qA1.w,qA2.x,qA2.y};
        unsigned int uB[10] = {qB0.x,qB0.y,qB0.z,qB0.w,qB1.x,qB1.y,qB1.z,qB1.w,qB2.x,qB2.y};
        float a0A = b0, a1A = b1, a0B = b0, a1B = b1;
        #pragma unroll
        for (int r = 0; r < 10; ++r) {
            h16x2 fA = u2h2(uA[r]);
            h16x2 fB = u2h2(uB[r]);
            a0A = fdot2(fA, w0p[r], a0A);
            a1A = fdot2(fA, w1p[r], a1A);
            a0B = fdot2(fB, w0p[r], a0B);
            a1B = fdot2(fB, w1p[r], a1B);
        }
        float rcA = __uint_as_float(qA2.w), rcB = __uint_as_float(qB2.w);
        float wv0A = ssp(a0A) * rcA, wv1A = ssp(a1A) * rcA;
        float wv0B = ssp(a0B) * rcB, wv1B = ssp(a1B) * rcB;
        unsigned int hA = hb32[(size_t)(int)qA2.z * 64 + lane];
        unsigned int hB = hb32[(size_t)(int)qB2.z * 64 + lane];
        acc0 += __uint_as_float(hA << 16) * wv0A + __uint_as_float(hB << 16) * wv0B;
        acc1 += __uint_as_float(hA & 0xffff0000u) * wv1A + __uint_as_float(hB & 0xffff0000u) * wv1B;
    }
    if (s < ce) {
        const uint4* pA = pay + (size_t)s * 3;
        uint4 q0 = pA[0], q1 = pA[1], q2 = pA[2];
        unsigned int u[10] = {q0.x,q0.y,q0.z,q0.w,q1.x,q1.y,q1.z,q1.w,q2.x,q2.y};
        float a0 = b0, a1 = b1;
        #pragma unroll
        for (int r = 0; r < 10; ++r) {
            h16x2 f = u2h2(u[r]);
            a0 = fdot2(f, w0p[r], a0);
            a1 = fdot2(f, w1p[r], a1);
        }
        float rc = __uint_as_float(q2.w);
        float wv0 = ssp(a0) * rc, wv1 = ssp(a1) * rc;
        unsigned int h = hb32[(size_t)(int)q2.z * 64 + lane];
        acc0 += __uint_as_float(h << 16) * wv0;
        acc1 += __uint_as_float(h & 0xffff0000u) * wv1;
    }

    *(float2*)&agg[(size_t)wave * 128 + c0] = make_float2(acc0, acc1);
}

// ---------- TIER-2 FALLBACK (proven): perm-indirected segment ----------
__global__ __launch_bounds__(256) void scatter_kernel(
    const int* __restrict__ idx_i, int* __restrict__ cur, int* __restrict__ perm,
    int n_pairs, int n_atoms)
{
    for (int p = blockIdx.x * 256 + threadIdx.x; p < n_pairs; p += gridDim.x * 256) {
        int ai = idx_i[p];
        if ((unsigned)ai < (unsigned)n_atoms) {
            int pos = atomicAdd(&cur[ai], 1);
            perm[pos] = p;
        }
    }
}

__global__ __launch_bounds__(256) void segment_kernel(
    const float* __restrict__ f_ij, const int* __restrict__ idx_j,
    const float* __restrict__ rcut, const float* __restrict__ W_f,
    const float* __restrict__ b_f, const unsigned short* __restrict__ hb,
    const int* __restrict__ offs, const int* __restrict__ perm,
    float* __restrict__ agg, int n_atoms)
{
    const int wave = (blockIdx.x * 256 + threadIdx.x) >> 6;
    const int lane = threadIdx.x & 63;
    if (wave >= n_atoms) return;

    float w0[20], w1[20];
    #pragma unroll
    for (int r = 0; r < 20; ++r) {
        w0[r] = W_f[lane * 20 + r];
        w1[r] = W_f[(lane + 64) * 20 + r];
    }
    const float b0 = b_f[lane], b1 = b_f[lane + 64];

    const int cs = offs[wave], ce = offs[wave + 1];
    float acc0 = 0.f, acc1 = 0.f;

    int s = cs;
    for (; s + 2 <= ce; s += 2) {
        int pA = perm[s], pB = perm[s + 1];
        int ajA = idx_j[pA], ajB = idx_j[pB];
        float rcA = rcut[pA], rcB = rcut[pB];
        const float4* frA = (const float4*)(f_ij + (size_t)pA * 20);
        const float4* frB = (const float4*)(f_ij + (size_t)pB * 20);
        float a0A = b0, a1A = b1, a0B = b0, a1B = b1;
        #pragma unroll
        for (int q = 0; q < 5; ++q) {
            float4 fA = frA[q], fB = frB[q];
            a0A += fA.x * w0[4*q+0]; a1A += fA.x * w1[4*q+0];
            a0A += fA.y * w0[4*q+1]; a1A += fA.y * w1[4*q+1];
            a0A += fA.z * w0[4*q+2]; a1A += fA.z * w1[4*q+2];
            a0A += fA.w * w0[4*q+3]; a1A += fA.w * w1[4*q+3];
            a0B += fB.x * w0[4*q+0]; a1B += fB.x * w1[4*q+0];
            a0B += fB.y * w0[4*q+1]; a1B += fB.y * w1[4*q+1];
            a0B += fB.z * w0[4*q+2]; a1B += fB.z * w1[4*q+2];
            a0B += fB.w * w0[4*q+3]; a1B += fB.w * w1[4*q+3];
        }
        float wv0A = ssp(a0A) * rcA, wv1A = ssp(a1A) * rcA;
        float wv0B = ssp(a0B) * rcB, wv1B = ssp(a1B) * rcB;
        float h0A = braw2f(hb[(size_t)ajA * 128 + lane]);
        float h1A = braw2f(hb[(size_t)ajA * 128 + 64 + lane]);
        float h0B = braw2f(hb[(size_t)ajB * 128 + lane]);
        float h1B = braw2f(hb[(size_t)ajB * 128 + 64 + lane]);
        acc0 += h0A * wv0A + h0B * wv0B;
        acc1 += h1A * wv1A + h1B * wv1B;
    }
    if (s < ce) {
        int p = perm[s];
        int aj = idx_j[p];
        float rc = rcut[p];
        const float4* fr = (const float4*)(f_ij + (size_t)p * 20);
        float a0 = b0, a1 = b1;
        #pragma unroll
        for (int q = 0; q < 5; ++q) {
            float4 fv = fr[q];
            a0 += fv.x * w0[4*q+0]; a1 += fv.x * w1[4*q+0];
            a0 += fv.y * w0[4*q+1]; a1 += fv.y * w1[4*q+1];
            a0 += fv.z * w0[4*q+2]; a1 += fv.z * w1[4*q+2];
            a0 += fv.w * w0[4*q+3]; a1 += fv.w * w1[4*q+3];
        }
        float wv0 = ssp(a0) * rc, wv1 = ssp(a1) * rc;
        acc0 += braw2f(hb[(size_t)aj * 128 + lane]) * wv0;
        acc1 += braw2f(hb[(size_t)aj * 128 + 64 + lane]) * wv1;
    }

    agg[(size_t)wave * 128 + lane]      = acc0;
    agg[(size_t)wave * 128 + 64 + lane] = acc1;
}

static inline size_t align_up(size_t v, size_t a) { return (v + a - 1) & ~(a - 1); }

extern "C" void kernel_launch(void* const* d_in, const int* in_sizes, int n_in,
                              void* d_out, int out_size, void* d_ws, size_t ws_size,
                              hipStream_t stream) {
    const float* x     = (const float*)d_in[0];
    const float* f_ij  = (const float*)d_in[1];
    const int*   idx_i = (const int*)d_in[2];
    const int*   idx_j = (const int*)d_in[3];
    const float* rcut  = (const float*)d_in[4];
    const float* W_in  = (const float*)d_in[5];
    const float* b_in  = (const float*)d_in[6];
    const float* W_f   = (const float*)d_in[7];
    const float* b_f   = (const float*)d_in[8];
    const float* W_out = (const float*)d_in[9];
    const float* b_out = (const float*)d_in[10];

    const int n_atoms = in_sizes[0] / 128;   // 40000
    const int n_pairs = in_sizes[2];         // 640000
    const int nscan = (n_atoms + 1023) / 1024;
    const int mfma_grid = (n_atoms + 63) / 64;

    // Tier-1 ws layout (payload path)
    size_t off_hb   = 0;
    size_t off_offs = align_up(off_hb + (size_t)n_atoms * 128 * 2, 16);
    size_t off_cur  = align_up(off_offs + (size_t)(n_atoms + 1) * 4, 16);
    size_t off_part = align_up(off_cur + (size_t)n_atoms * 4, 16);
    size_t off_pay  = align_up(off_part + (size_t)nscan * 4, 64);
    size_t need_pay = off_pay + (size_t)n_pairs * 48 + 816;

    if (ws_size >= need_pay) {
        // ---------- tier-1: f16 payload + fdot2 segment ----------
        unsigned short* hb = (unsigned short*)((char*)d_ws + off_hb);
        int*  offs = (int*)((char*)d_ws + off_offs);
        int*  cur  = (int*)((char*)d_ws + off_cur);
        int*  part = (int*)((char*)d_ws + off_part);
        uint4* pay = (uint4*)((char*)d_ws + off_pay);
        float* agg = (float*)d_out;

        linear128_mfma_kernel<false, true><<<dim3(mfma_grid), dim3(256), 0, stream>>>(
            x, W_in, b_in, (void*)hb, n_atoms);

        zero_int_kernel<<<dim3((n_atoms + 255) / 256), dim3(256), 0, stream>>>(cur, n_atoms);
        hist_kernel<<<dim3(1024), dim3(256), 0, stream>>>(idx_i, cur, n_pairs, n_atoms);
        scan1_kernel<<<dim3(nscan), dim3(1024), 0, stream>>>(cur, offs, part, n_atoms);
        scan2_kernel<<<dim3(1), dim3(64), 0, stream>>>(part, offs, nscan, n_atoms);
        scan3_kernel<<<dim3(nscan), dim3(1024), 0, stream>>>(offs, cur, part, n_atoms);
        scatter_pay_kernel<<<dim3(1024), dim3(256), 0, stream>>>(
            f_ij, idx_i, idx_j, rcut, cur, pay, n_pairs, n_atoms);

        segment_pay_f16_kernel<<<dim3((n_atoms + 3) / 4), dim3(256), 0, stream>>>(
            pay, W_f, b_f, (const unsigned int*)hb, offs, agg, n_atoms);

        linear128_mfma_kernel<true, false><<<dim3(mfma_grid), dim3(256), 0, stream>>>(
            agg, W_out, b_out, d_out, n_atoms);
    } else {
        // ---------- tier-2: exact round-8 pipeline (proven 419 µs) ----------
        size_t o_h    = 0;
        size_t o_offs = o_h + (size_t)n_atoms * 128 * 2;
        size_t o_cur  = o_offs + (size_t)(n_atoms + 1) * 4;
        size_t o_perm = o_cur + (size_t)n_atoms * 4;
        size_t o_part = o_perm + (size_t)n_pairs * 4;
        unsigned short* hb = (unsigned short*)((char*)d_ws + o_h);
        int* offs = (int*)((char*)d_ws + o_offs);
        int* cur  = (int*)((char*)d_ws + o_cur);
        int* perm = (int*)((char*)d_ws + o_perm);
        int* part = (int*)((char*)d_ws + o_part);
        float* agg = (float*)d_out;

        linear128_mfma_kernel<false, true><<<dim3(mfma_grid), dim3(256), 0, stream>>>(
            x, W_in, b_in, (void*)hb, n_atoms);

        zero_int_kernel<<<dim3((n_atoms + 255) / 256), dim3(256), 0, stream>>>(cur, n_atoms);
        hist_kernel<<<dim3(1024), dim3(256), 0, stream>>>(idx_i, cur, n_pairs, n_atoms);
        scan1_kernel<<<dim3(nscan), dim3(1024), 0, stream>>>(cur, offs, part, n_atoms);
        scan2_kernel<<<dim3(1), dim3(64), 0, stream>>>(part, offs, nscan, n_atoms);
        scan3_kernel<<<dim3(nscan), dim3(1024), 0, stream>>>(offs, cur, part, n_atoms);
        scatter_kernel<<<dim3(1024), dim3(256), 0, stream>>>(idx_i, cur, perm, n_pairs, n_atoms);

        segment_kernel<<<dim3((n_atoms + 3) / 4), dim3(256), 0, stream>>>(
            f_ij, idx_j, rcut, W_f, b_f, hb, offs, perm, agg, n_atoms);

        linear128_mfma_kernel<true, false><<<dim3(mfma_grid), dim3(256), 0, stream>>>(
            agg, W_out, b_out, d_out, n_atoms);
    }
}